// Round 11
// baseline (286.524 us; speedup 1.0000x reference)
//
#include <hip/hip_runtime.h>
#include <hip/hip_bf16.h>
#include <cmath>
#include <cstdint>

// CrossAttention: out = softmax((x Wq)(ctx Wk)^T * 1/8) (ctx Wv) Wo + bo
// b=2, n=m=4096, H=8, D=64, qdim=1024, cdim=768, inner=512.
// Round 19 = R10 GEMMs/prep + BARRIER-FREE attn:
//  - attn: 4 waves = 2 q-halves x 2 kv-halves. Each wave owns 64 q-rows and
//    one 2048-kv half, reading K/V fragments DIRECTLY from global/L2 (no
//    shared LDS staging, NO __syncthreads in the main loop -> waves fully
//    desynchronized; the per-iter barrier straggle, ~3300cy vs ~500cy pipe
//    work, was the last untested structural suspect). Cost: 2x K/V L2 reads
//    (1.05 GB, ~30us L2 floor). kv-half partials combined once at the end
//    via LDS (single barrier). PsA per-wave-private [2][128][40] (16B-aligned
//    stride), lgkmcnt(0) fence as before. Per-wave MFMA/exp2 counts identical.

using bf16_t = __hip_bfloat16;
typedef __bf16 bf16x8 __attribute__((ext_vector_type(8)));
typedef float  f32x4  __attribute__((ext_vector_type(4)));

static constexpr int BATCH = 2;
static constexpr int NQ    = 4096;
static constexpr int NKV   = 4096;
static constexpr int NH    = 8;
static constexpr int DH    = 64;
static constexpr int INNER = NH * DH;   // 512
static constexpr int QDIM  = 1024;
static constexpr int CDIM  = 768;
// Q is pre-scaled by SCALE*log2(e) so softmax uses exp2 directly.
static constexpr float QSCALE = 0.125f * 1.4426950408889634f;  // 0.18033688

#define MFMA_BF16(a, b, c) __builtin_amdgcn_mfma_f32_16x16x32_bf16((a), (b), (c), 0, 0, 0)

__device__ __forceinline__ float fast_exp2(float x) {
  return __builtin_amdgcn_exp2f(x);
}

// async global->LDS, 16B per lane; LDS dest is wave-uniform base + lane*16 (HW).
__device__ __forceinline__ void gload16(const bf16_t* g, bf16_t* l) {
  __builtin_amdgcn_global_load_lds((__attribute__((address_space(1))) void*)(g),
                                   (__attribute__((address_space(3))) void*)(l),
                                   16, 0, 0);
}

// ---------- fused prep: f32->bf16 cast of x and ctx + 4 weight transposes ----------
__global__ __launch_bounds__(256) void prep_kernel(const float* __restrict__ x,
                                                   const float* __restrict__ ctx,
                                                   const float* __restrict__ Wq,
                                                   const float* __restrict__ Wk,
                                                   const float* __restrict__ Wv,
                                                   const float* __restrict__ Wo,
                                                   bf16_t* __restrict__ xb,
                                                   bf16_t* __restrict__ ctxb,
                                                   bf16_t* __restrict__ WqT,
                                                   bf16_t* __restrict__ WkvT,
                                                   bf16_t* __restrict__ WoT) {
  constexpr int XN8 = BATCH * NQ * QDIM / 8;   // 1048576 (4096 blocks)
  constexpr int CN8 = BATCH * NKV * CDIM / 8;  // 786432  (3072 blocks)
  constexpr int CAST_BLK = (XN8 + CN8) / 256;  // 7168
  __shared__ float tile[32][33];
  const int bid = blockIdx.x;
  if (bid < CAST_BLK) {
    int id = bid * 256 + threadIdx.x;
    const float* in;
    bf16_t* out;
    if (id < XN8) {
      in = x; out = xb;
    } else {
      id -= XN8; in = ctx; out = ctxb;
    }
    float4 a = ((const float4*)in)[2 * id];
    float4 b = ((const float4*)in)[2 * id + 1];
    bf16_t t[8] = {__float2bfloat16(a.x), __float2bfloat16(a.y), __float2bfloat16(a.z),
                   __float2bfloat16(a.w), __float2bfloat16(b.x), __float2bfloat16(b.y),
                   __float2bfloat16(b.z), __float2bfloat16(b.w)};
    ((uint4*)out)[id] = *(const uint4*)t;
    return;
  }
  int wb = bid - CAST_BLK;
  const float* W;
  bf16_t* WT;
  int K, N;
  if (wb < 512) {
    W = Wq; WT = WqT; K = QDIM; N = INNER;
  } else if (wb < 896) {
    wb -= 512; W = Wk; WT = WkvT; K = CDIM; N = INNER;
  } else if (wb < 1280) {
    wb -= 896; W = Wv; WT = WkvT + (size_t)INNER * CDIM; K = CDIM; N = INNER;
  } else {
    wb -= 1280; W = Wo; WT = WoT; K = INNER; N = QDIM;
  }
  const int bnt = N / 32;
  const int bn = (wb % bnt) * 32, bk = (wb / bnt) * 32;
  const int tx = threadIdx.x & 31, ty = threadIdx.x >> 5;  // ty 0..7
  for (int yy = ty; yy < 32; yy += 8)
    tile[yy][tx] = W[(size_t)(bk + yy) * N + bn + tx];
  __syncthreads();
  for (int yy = ty; yy < 32; yy += 8)
    WT[(size_t)(bn + yy) * K + bk + tx] = __float2bfloat16(tile[tx][yy]);
}

// ---------- 128x128 MFMA GEMM core, triple-buffer + counted vmcnt ----------
__device__ __forceinline__ void gemm128_core(const bf16_t* __restrict__ A,
                                             const bf16_t* __restrict__ WT, int K,
                                             int m0, int n0, int tid,
                                             f32x4 (&acc)[4][4],
                                             bf16_t (*As)[128][32],
                                             bf16_t (*Bs)[128][32]) {
  const int lane = tid & 63, wave = tid >> 6;
  const int lane15 = lane & 15, quad = lane >> 4;
  const int wm = (wave >> 1) * 64, wn = (wave & 1) * 64;
  const int srow = tid >> 2;                                // 0..63 (+64 chunk)
  const int scol = ((tid & 3) ^ ((srow >> 1) & 3)) * 8;     // inverse-swizzled src
  const bf16_t* aptr = A + (size_t)(m0 + srow) * K + scol;
  const bf16_t* bptr = WT + (size_t)(n0 + srow) * K + scol;
  bf16_t* const ab = &As[0][wave * 16][0];   // wave-uniform base (+lane*16 by HW)
  bf16_t* const bb = &Bs[0][wave * 16][0];
  constexpr int BUF = 128 * 32;

  auto stage = [&](int t) {
    const int c = (t % 3) * BUF;
    const bf16_t* as = aptr + t * 32;
    const bf16_t* bs = bptr + t * 32;
    gload16(as, ab + c);
    gload16(as + (size_t)64 * K, ab + c + 64 * 32);
    gload16(bs, bb + c);
    gload16(bs + (size_t)64 * K, bb + c + 64 * 32);
  };

  const int T = K / 32;
  stage(0);
  stage(1);
  for (int t = 0; t < T; ++t) {
    const int cur = t % 3;
    if (t < T - 1) {
      asm volatile("s_waitcnt vmcnt(4)" ::: "memory");
    } else {
      asm volatile("s_waitcnt vmcnt(0)" ::: "memory");
    }
    asm volatile("s_barrier" ::: "memory");
    if (t + 2 < T) stage(t + 2);
    bf16x8 af[4], bfr[4];
#pragma unroll
    for (int i = 0; i < 4; ++i) {
      const int row = wm + i * 16 + lane15;
      af[i] = *reinterpret_cast<const bf16x8*>(
          &As[cur][0][0] + row * 32 + ((quad * 8) ^ (((row >> 1) & 3) * 8)));
    }
#pragma unroll
    for (int j = 0; j < 4; ++j) {
      const int row = wn + j * 16 + lane15;
      bfr[j] = *reinterpret_cast<const bf16x8*>(
          &Bs[cur][0][0] + row * 32 + ((quad * 8) ^ (((row >> 1) & 3) * 8)));
    }
#pragma unroll
    for (int i = 0; i < 4; ++i)
#pragma unroll
      for (int j = 0; j < 4; ++j) acc[i][j] = MFMA_BF16(af[i], bfr[j], acc[i][j]);
  }
}

// ---------- merged Q + KV projection: 768 blocks, XCD-chunked swizzle ----------
__global__ __launch_bounds__(256, 3) void qkv_gemm_kernel(const bf16_t* __restrict__ xb,
                                                          const bf16_t* __restrict__ ctxb,
                                                          const bf16_t* __restrict__ WqT,
                                                          const bf16_t* __restrict__ WkvT,
                                                          bf16_t* __restrict__ qob,
                                                          bf16_t* __restrict__ kb,
                                                          bf16_t* __restrict__ vtb) {
  __shared__ __align__(16) bf16_t As[3][128][32];   // 24 KB
  __shared__ __align__(16) bf16_t Bs[3][128][32];   // 24 KB
  const int tid = threadIdx.x;
  const int bid = blockIdx.x;                 // 768 = 8 XCDs x 96
  const int vb = (bid & 7) * 96 + (bid >> 3); // bijective (768 % 8 == 0)
  const int bx = vb / 12, bsel = vb % 12;
  const bool isq = bsel < 4;
  const bf16_t* A  = isq ? xb : ctxb;
  const bf16_t* WT = isq ? WqT : WkvT;
  const int K  = isq ? QDIM : CDIM;
  const int m0 = bx * 128;
  const int n0 = (isq ? bsel : bsel - 4) * 128;

  const f32x4 vzero = {0.f, 0.f, 0.f, 0.f};
  f32x4 acc[4][4];
  for (int i = 0; i < 4; ++i)
    for (int j = 0; j < 4; ++j) acc[i][j] = vzero;

  gemm128_core(A, WT, K, m0, n0, tid, acc, As, Bs);

  // epilogue: C/D layout col=lane&15, row=quad*4+reg  [verified m89/m91]
  const int lane = tid & 63, wave = tid >> 6;
  const int lane15 = lane & 15, quad = lane >> 4;
  const int wm = (wave >> 1) * 64, wn = (wave & 1) * 64;
  for (int i = 0; i < 4; ++i) {
    int gm = m0 + wm + i * 16 + quad * 4;
    for (int j = 0; j < 4; ++j) {
      int gn = n0 + wn + j * 16 + lane15;
      for (int r = 0; r < 4; ++r) {
        float v = acc[i][j][r];
        if (isq) {
          qob[(size_t)(gm + r) * INNER + gn] = __float2bfloat16(v * QSCALE);
        } else if (gn < INNER) {
          kb[(size_t)(gm + r) * INNER + gn] = __float2bfloat16(v);
        } else {
          int gmr = gm + r;  // vt[b][c][mi], b = gmr/4096, mi = gmr%4096
          vtb[((size_t)(gmr >> 12) * INNER + (gn - INNER)) * (size_t)NKV +
              (gmr & 4095)] = __float2bfloat16(v);
        }
      }
    }
  }
}

// ---------- output projection: 512 blocks, XCD-chunked swizzle ----------
__global__ __launch_bounds__(256, 3) void out_gemm_kernel(const bf16_t* __restrict__ A,
                                                          const bf16_t* __restrict__ WT,
                                                          float* __restrict__ C,
                                                          const float* __restrict__ bias) {
  __shared__ __align__(16) bf16_t As[3][128][32];
  __shared__ __align__(16) bf16_t Bs[3][128][32];
  const int tid = threadIdx.x;
  const int bid = blockIdx.x;                 // 512 = 8 XCDs x 64
  const int vb = (bid & 7) * 64 + (bid >> 3); // bijective
  const int m0 = (vb >> 3) * 128, n0 = (vb & 7) * 128;  // 8 n-tiles share m-panel
  constexpr int K = INNER, N = QDIM;

  const f32x4 vzero = {0.f, 0.f, 0.f, 0.f};
  f32x4 acc[4][4];
  for (int i = 0; i < 4; ++i)
    for (int j = 0; j < 4; ++j) acc[i][j] = vzero;

  gemm128_core(A, WT, K, m0, n0, tid, acc, As, Bs);

  const int lane = tid & 63, wave = tid >> 6;
  const int lane15 = lane & 15, quad = lane >> 4;
  const int wm = (wave >> 1) * 64, wn = (wave & 1) * 64;
  float bv[4];
  for (int j = 0; j < 4; ++j) bv[j] = bias[n0 + wn + j * 16 + lane15];
  for (int i = 0; i < 4; ++i) {
    int gm = m0 + wm + i * 16 + quad * 4;
    for (int j = 0; j < 4; ++j) {
      int gn = n0 + wn + j * 16 + lane15;
      for (int r = 0; r < 4; ++r)
        C[(size_t)(gm + r) * N + gn] = acc[i][j][r] + bv[j];
    }
  }
}

// ---------- flash attention: BARRIER-FREE, one (b, h, 128-row Q tile) per block ----
// 256 threads = 4 waves = 2 q-halves (64 rows each) x 2 kv-halves (2048 kv).
// Each wave reads K/V fragments DIRECTLY from global (L2-resident per XCD via
// the XCD-chunked swizzle): no shared staging, no main-loop __syncthreads --
// waves run fully desynchronized. Per wave-iter (32 kv x 64 q): 16 QK^T MFMA,
// 32 exp2 + 8 b64 PsA writes (wave-private rows, lgkmcnt fence), 4 pf b128
// reads, 16 PV + 4 ones-MFMA (l). kv-half partials combined once at the end
// through LDS scratch (the kernel's only barrier).
__global__ __launch_bounds__(256, 2) void attn_kernel(const bf16_t* Qg /*[b][m][c]*/,
                                                      const bf16_t* __restrict__ Kg /*[b][m][c]*/,
                                                      const bf16_t* __restrict__ Vtg /*[b][c][m]*/,
                                                      bf16_t* Og /*[b][m][c], may alias Qg*/) {
  __shared__ __align__(16) bf16_t PsA[2][128][40];  // 20 KB; 80B row stride (16B-mult)
  __shared__ __align__(16) float scrO[8192];        // 32 KB kv-half O partials
  __shared__ float scrL[128];                       // l partials

  const int tid = threadIdx.x;
  const int lane = tid & 63, wave = tid >> 6;     // wave 0..3
  const int lane15 = lane & 15, quad = lane >> 4;
  const int qhalf = wave >> 1, vh = wave & 1;     // q-half / kv-half
  const int qr0 = qhalf * 64;
  const int bid = blockIdx.x;                     // 512 = 8 XCDs x 64
  const int vb = (bid & 7) * 64 + (bid >> 3);     // bijective (512 % 8 == 0)
  const int qt = vb & 31, hb = vb >> 5;           // qt fastest within (h,b)
  const int h = hb & 7, b = hb >> 3;
  const int q0 = qt * 128;

  const size_t qbase  = ((size_t)b * NQ + q0) * INNER + h * DH;
  const size_t kbase  = ((size_t)b * NKV) * INNER + h * DH;
  const size_t vtbase = ((size_t)(b * NH + h) * DH) * NKV;

  // Q fragments (B-operand): n=q=lane15 (within qh4 tile), k = ks*32+quad*8
  bf16x8 qf[4][2];  // [qh4][ks]
#pragma unroll
  for (int qh4 = 0; qh4 < 4; ++qh4)
#pragma unroll
    for (int ks = 0; ks < 2; ++ks)
      qf[qh4][ks] = *reinterpret_cast<const bf16x8*>(
          Qg + qbase + (size_t)(qr0 + qh4 * 16 + lane15) * INNER + ks * 32 + quad * 8);

  bf16x8 ones;
#pragma unroll
  for (int i = 0; i < 8; ++i) ones[i] = (__bf16)1.0f;

  const f32x4 vzero = {0.f, 0.f, 0.f, 0.f};
  f32x4 acc_o[4][4];   // [qh4][dj]
  f32x4 acc_l[4];      // [qh4]
#pragma unroll
  for (int qh4 = 0; qh4 < 4; ++qh4) {
    acc_l[qh4] = vzero;
    for (int dj = 0; dj < 4; ++dj) acc_o[qh4][dj] = vzero;
  }

  const int kvbase = vh * (NKV / 2);  // this wave's kv half
  // K A-frag (t, mt, ks): m=kv = mt*16+lane15, k=d = ks*32+quad*8
  auto kfrag = [&](int t, int mt, int ks) {
    return *reinterpret_cast<const bf16x8*>(
        Kg + kbase + (size_t)(kvbase + t * 32 + mt * 16 + lane15) * INNER +
        ks * 32 + quad * 8);
  };
  // V B-frag (t, dj): n=d = dj*16+lane15, k=kv = quad*8+j
  auto vfrag = [&](int t, int dj) {
    return *reinterpret_cast<const bf16x8*>(
        Vtg + vtbase + (size_t)(dj * 16 + lane15) * NKV + kvbase + t * 32 + quad * 8);
  };

  bf16x8 kc[2][2];  // current K frags [mt][ks]
#pragma unroll
  for (int mt = 0; mt < 2; ++mt)
#pragma unroll
    for (int ks = 0; ks < 2; ++ks) kc[mt][ks] = kfrag(0, mt, ks);

  constexpr int T = (NKV / 2) / 32;  // 64
  for (int t = 0; t < T; ++t) {
    // issue this iter's V loads early: land during QK^T + softmax
    bf16x8 vf[4];
#pragma unroll
    for (int dj = 0; dj < 4; ++dj) vf[dj] = vfrag(t, dj);

    // S^T = K Q^T for this wave's 32 kv x 64 q
    f32x4 st[4][2];  // [qh4][mt]
#pragma unroll
    for (int qh4 = 0; qh4 < 4; ++qh4)
      for (int mt = 0; mt < 2; ++mt) st[qh4][mt] = vzero;
    __builtin_amdgcn_s_setprio(1);
#pragma unroll
    for (int ks = 0; ks < 2; ++ks)
#pragma unroll
      for (int mt = 0; mt < 2; ++mt)
#pragma unroll
        for (int qh4 = 0; qh4 < 4; ++qh4)
          st[qh4][mt] = MFMA_BF16(kc[mt][ks], qf[qh4][ks], st[qh4][mt]);
    __builtin_amdgcn_s_setprio(0);

    // prefetch next iter's K frags during softmax
    bf16x8 kn[2][2];
    if (t + 1 < T) {
#pragma unroll
      for (int mt = 0; mt < 2; ++mt)
#pragma unroll
        for (int ks = 0; ks < 2; ++ks) kn[mt][ks] = kfrag(t + 1, mt, ks);
    }

    // softmax: lane holds q = qr0+qh4*16+lane15, kv = mt*16+quad*4+r
    // -> pack 4 kv-consecutive p as one b64 write in A-operand layout
#pragma unroll
    for (int qh4 = 0; qh4 < 4; ++qh4)
#pragma unroll
      for (int mt = 0; mt < 2; ++mt) {
        bf16_t t4[4];
        for (int r = 0; r < 4; ++r)
          t4[r] = __float2bfloat16(fast_exp2(st[qh4][mt][r]));
        *(uint2*)&PsA[vh][qr0 + qh4 * 16 + lane15][mt * 16 + quad * 4] =
            *(const uint2*)t4;
      }
    // PsA rows are written and read by THIS wave only: LDS-write completion
    // fence suffices (no barrier, doesn't drain the kf/vf loads).
    asm volatile("s_waitcnt lgkmcnt(0)" ::: "memory");

    // O += P V ; l += P 1  (pf: A-operand m=q, k=32 kv = quad*8+j)
    __builtin_amdgcn_s_setprio(1);
#pragma unroll
    for (int qh4 = 0; qh4 < 4; ++qh4) {
      bf16x8 pf = *reinterpret_cast<const bf16x8*>(
          &PsA[vh][qr0 + qh4 * 16 + lane15][quad * 8]);
      acc_l[qh4] = MFMA_BF16(pf, ones, acc_l[qh4]);
#pragma unroll
      for (int dj = 0; dj < 4; ++dj)
        acc_o[qh4][dj] = MFMA_BF16(pf, vf[dj], acc_o[qh4][dj]);
    }
    __builtin_amdgcn_s_setprio(0);

    if (t + 1 < T) {
#pragma unroll
      for (int mt = 0; mt < 2; ++mt)
#pragma unroll
        for (int ks = 0; ks < 2; ++ks) kc[mt][ks] = kn[mt][ks];
    }
  }

  // epilogue: combine kv-half partials (vh=1 -> LDS -> vh=0); the only barrier
  if (vh == 1) {
#pragma unroll
    for (int qh4 = 0; qh4 < 4; ++qh4)
#pragma unroll
      for (int dj = 0; dj < 4; ++dj)
        for (int r = 0; r < 4; ++r)
          scrO[((((qhalf * 4 + qh4) * 4 + dj) * 4) + r) * 64 + lane] =
              acc_o[qh4][dj][r];
    if (lane15 == 0)
#pragma unroll
      for (int qh4 = 0; qh4 < 4; ++qh4)
        for (int r = 0; r < 4; ++r)
          scrL[qr0 + qh4 * 16 + quad * 4 + r] = acc_l[qh4][r];
  }
  __syncthreads();
  if (vh == 0) {
#pragma unroll
    for (int qh4 = 0; qh4 < 4; ++qh4)
      for (int r = 0; r < 4; ++r) {
        int row = qr0 + qh4 * 16 + quad * 4 + r;
        float lt = acc_l[qh4][r] + scrL[row];
        float inv = 1.f / lt;
#pragma unroll
        for (int dj = 0; dj < 4; ++dj) {
          float o = acc_o[qh4][dj][r] +
                    scrO[((((qhalf * 4 + qh4) * 4 + dj) * 4) + r) * 64 + lane];
          Og[qbase + (size_t)row * INNER + dj * 16 + lane15] =
              __float2bfloat16(o * inv);
        }
      }
  }
}

extern "C" void kernel_launch(void* const* d_in, const int* in_sizes, int n_in,
                              void* d_out, int out_size, void* d_ws, size_t ws_size,
                              hipStream_t stream) {
  (void)in_sizes; (void)n_in; (void)out_size; (void)ws_size;
  const float* x   = (const float*)d_in[0];  // [2][4096][1024]
  const float* ctx = (const float*)d_in[1];  // [2][4096][768]
  const float* Wq  = (const float*)d_in[2];  // [1024][512]
  const float* Wk  = (const float*)d_in[3];  // [768][512]
  const float* Wv  = (const float*)d_in[4];  // [768][512]
  const float* Wo  = (const float*)d_in[5];  // [512][1024]
  const float* bo  = (const float*)d_in[6];  // [1024]
  float* out = (float*)d_out;                // [2][4096][1024], 33.5 MB

  // workspace layout (~28.8 MB)
  char* ws = (char*)d_ws;
  size_t off = 0;
  auto take = [&](size_t nelem) { bf16_t* p = (bf16_t*)(ws + off); off += nelem * 2; return p; };
  bf16_t* WqT  = take((size_t)INNER * QDIM);        // [512][1024]
  bf16_t* WkvT = take((size_t)(2 * INNER) * CDIM);  // [1024][768]: Wk^T then Wv^T
  bf16_t* WoT  = take((size_t)QDIM * INNER);        // [1024][512]
  bf16_t* qob  = take((size_t)BATCH * NQ * INNER);  // Q (pre-scaled), later O
  bf16_t* kb   = take((size_t)BATCH * NKV * INNER);
  bf16_t* vtb  = take((size_t)BATCH * INNER * NKV); // V transposed [b][c][m]

  // bf16 copies of x/ctx live in d_out (dead until the final GEMM writes it):
  // xb 16.8 MB + ctxb 12.6 MB = 29.4 MB <= 33.5 MB.
  bf16_t* xb   = (bf16_t*)d_out;
  bf16_t* ctxb = xb + (size_t)BATCH * NQ * QDIM;

  // fused cast + weight transpose: 7168 cast blocks + 1792 transpose blocks
  prep_kernel<<<8960, 256, 0, stream>>>(x, ctx, Wq, Wk, Wv, Wo, xb, ctxb, WqT, WkvT, WoT);

  // merged Q + KV projections: 768 blocks (~3/CU at 48 KB LDS), XCD-swizzled
  qkv_gemm_kernel<<<768, 256, 0, stream>>>(xb, ctxb, WqT, WkvT, qob, kb, vtb);

  // attention; O overwrites Q in place (each block reads its Q rows before
  // writing O). 512 blocks, XCD-swizzled (2 (h,b) K/V sets per XCD).
  attn_kernel<<<512, 256, 0, stream>>>(qob, kb, vtb, qob);

  // output projection + bias (fp32 out): 128x128 tiles, 512 blocks, XCD-swizzled
  out_gemm_kernel<<<512, 256, 0, stream>>>(qob, WoT, out, bo);
}